// Round 9
// baseline (19145.462 us; speedup 1.0000x reference)
//
#include <hip/hip_runtime.h>
#include <hip/hip_fp16.h>

#define TT 2048
typedef unsigned int uint32;
typedef unsigned short ushort;

typedef _Float16 half2v __attribute__((ext_vector_type(2)));

#if defined(__has_builtin)
#  if __has_builtin(__builtin_amdgcn_fdot2)
#    define HAVE_DOT2 1
#  endif
#endif
#ifndef HAVE_DOT2
#  define HAVE_DOT2 0
#endif

// d_ws: WREGH uint32[176][1024]  (720896 B) — packed fp16 weight pairs,
// slot-major so each thread's stream is wsrc[slot*1024].
#define WREG_N (176 * 1024)

__device__ __forceinline__ float dot2(uint32 a, uint32 w, float c)
{
#if HAVE_DOT2
    return __builtin_amdgcn_fdot2(__builtin_bit_cast(half2v, a),
                                  __builtin_bit_cast(half2v, w), c, false);
#else
    half2v av = __builtin_bit_cast(half2v, a);
    half2v wv = __builtin_bit_cast(half2v, w);
    c = fmaf((float)av.x, (float)wv.x, c);      // clang folds to v_fma_mix
    return fmaf((float)av.y, (float)wv.y, c);
#endif
}

__device__ __forceinline__ uint32 pkh(float a, float b)
{
    __half ha = __float2half(a), hb = __float2half(b);
    ushort ua = *reinterpret_cast<ushort*>(&ha);
    ushort ub = *reinterpret_cast<ushort*>(&hb);
    return (uint32)ua | ((uint32)ub << 16);
}

// full cat index: [x 0:512 | s 512:768 | I 768:896]
__device__ __forceinline__ float getFull(const float* __restrict__ W_ih,
                                         const float* __restrict__ W_hh,
                                         int j, int k)
{
    if (k < 512) return W_ih[j * 640 + k];
    if (k < 768) return W_hh[j * 256 + (k - 512)];
    return W_ih[j * 640 + 512 + (k - 768)];
}

// Weight layout per thread tid in [0,1024):
//  A slots p in [0,112): j = tid>>2, q = tid&3, pair = 112q + p, k0 = 2*pair.
//  B slots in [112,176): s = slot-112, i = s>>2, m = s&3, n = tid>>1,
//    hh = tid&1, k0 = 128*hh + 8*i + 2*m   (W_out row n).
__global__ void prep_kernel(const float* __restrict__ W_ih,
                            const float* __restrict__ W_hh,
                            const float* __restrict__ W_out,
                            uint32* __restrict__ WREGH)
{
    int idx = blockIdx.x * blockDim.x + threadIdx.x;
    if (idx >= WREG_N) return;
    int tid  = idx & 1023;
    int slot = idx >> 10;
    float lo, hi;
    if (slot < 112) {
        int j = tid >> 2, q = tid & 3;
        int k0 = 224 * q + 2 * slot;
        lo = getFull(W_ih, W_hh, j, k0);
        hi = getFull(W_ih, W_hh, j, k0 + 1);
    } else {
        int s = slot - 112;
        int i = s >> 2, m = s & 3;
        int n = tid >> 1, hh = tid & 1;
        int k0 = 128 * hh + 8 * i + 2 * m;
        lo = W_out[n * 256 + k0];
        hi = W_out[n * 256 + k0 + 1];
    }
    WREGH[idx] = pkh(lo, hi);
}

// LDS-only barrier (shfl/ds are lgkm; global loads stay in flight).
__device__ __forceinline__ void bar_lds()
{
    asm volatile("s_waitcnt lgkmcnt(0)" ::: "memory");
    __builtin_amdgcn_s_barrier();
    asm volatile("" ::: "memory");
}

__global__ __launch_bounds__(1024, 4)
void scan_kernel(const float* __restrict__ I,
                 const float* __restrict__ b_ih, const float* __restrict__ b_hh,
                 const float* __restrict__ b_out, const float* __restrict__ A,
                 const uint32* __restrict__ WREGH,
                 float* __restrict__ out)
{
    // packed fp16 act pairs (pair index = cat k/2): x[0,256) s[256,384) I[384,448)
    __shared__ uint4 apk4[2][112];
    __shared__ uint4 s4pk[32];        // packed fp16 s pairs [0,128)
    __shared__ float xf32[2][512];    // exact f32 x state (recurrence stays f32)

    const int tid = threadIdx.x;
    const int b   = blockIdx.x;

    // ---- ALL weights -> VGPRs, pinned against rematerialization ----
    uint32 wA[112], wB[64];
    const uint32* wsrc = WREGH + tid;
    #pragma unroll
    for (int i = 0; i < 112; ++i) { wA[i] = wsrc[(size_t)i * 1024]; asm("" : "+v"(wA[i])); }
    #pragma unroll
    for (int i = 0; i < 64;  ++i) { wB[i] = wsrc[(size_t)(112 + i) * 1024]; asm("" : "+v"(wB[i])); }

    const int q  = tid & 3;        // A k-quarter (224 k each)
    const int jj = tid >> 2;       // A output row
    const int hh = tid & 1;        // B k-half (128 k each)
    const int nn = tid >> 1;       // B output row

    const float bs   = ((tid & 3) == 0) ? (b_ih[jj] + b_hh[jj]) : 0.f;
    const float bo_r = ((tid & 1) == 0) ? b_out[nn] : 0.f;
    const float Av_r = ((tid & 1) == 0) ? A[nn] : 0.f;

    const size_t iBase   = (size_t)b * TT * 128;
    const size_t outBase = (size_t)b * TT * 512;

    {   // init buffer 0: x=0 (pairs 0..255), s=0 (256..383), I(0) (384..447)
        uint32* a0p = (uint32*)&apk4[0][0];
        if (tid < 384) a0p[tid] = 0u;
        else if (tid < 448) {
            int m = tid - 384;
            a0p[tid] = pkh(I[iBase + 2 * m], I[iBase + 2 * m + 1]);
        }
        if (tid < 512) xf32[0][tid] = 0.f;
    }
    __syncthreads();

    for (int t = 0; t < TT; ++t) {
        const int par = t & 1;
        const uint4* rdp = apk4[par];
        uint32*      wrp = (uint32*)apk4[par ^ 1];

        // I(t+1): issue loads early, pack late (hides HBM under compute)
        float2 iv2 = make_float2(0.f, 0.f);
        if (tid < 64) {
            int tl = (t + 1 < TT) ? (t + 1) : t;
            iv2 = *(const float2*)(I + iBase + (size_t)tl * 128 + 2 * tid);
        }

        // ---- phase A: pre[jj], lane quad covers the full 896-k cat ----
        float a0 = 0.f, a1 = 0.f;
        #pragma unroll
        for (int i = 0; i < 28; ++i) {
            uint4 av = rdp[28 * q + i];      // 4 addrs/wave -> broadcast, 2-way free
            a0 = dot2(av.x, wA[4 * i + 0], a0);
            a1 = dot2(av.y, wA[4 * i + 1], a1);
            a0 = dot2(av.z, wA[4 * i + 2], a0);
            a1 = dot2(av.w, wA[4 * i + 3], a1);
        }
        float acc = a0 + a1;
        acc += __shfl_xor(acc, 1);
        acc += __shfl_xor(acc, 2);           // full pre at all quad lanes

        float sn = 0.f;
        if ((tid & 3) == 0) {
            float pre = acc + bs;
            // tanh(x) = 1 - 2/(exp(2x)+1): exact identity, branch-free
            float e = __expf(2.f * pre);
            sn = 1.f - 2.f / (e + 1.f);
        }
        {   // pack s pairs: leaders tid=8m (jj=2m) and tid=8m+4 (jj=2m+1)
            float sno = __shfl_xor(sn, 4);
            if ((tid & 7) == 0) {
                uint32 sp = pkh(sn, sno);
                ((uint32*)s4pk)[jj >> 1] = sp;   // for phase B
                wrp[256 + (jj >> 1)]     = sp;   // s state for next step's A
            }
        }
        bar_lds();                           // (1) s ready

        // ---- phase B: f[nn], lane pair covers k=256 ----
        float c0 = 0.f, c1 = 0.f;
        #pragma unroll
        for (int i = 0; i < 16; ++i) {
            uint4 sv = s4pk[16 * hh + i];    // 2 addrs/wave -> broadcast
            c0 = dot2(sv.x, wB[4 * i + 0], c0);
            c1 = dot2(sv.y, wB[4 * i + 1], c1);
            c0 = dot2(sv.z, wB[4 * i + 2], c0);
            c1 = dot2(sv.w, wB[4 * i + 3], c1);
        }
        float f = c0 + c1;
        f += __shfl_xor(f, 1);               // full k-sum at both pair lanes

        float xn = 0.f;
        if ((tid & 1) == 0) {
            float ff = fmaxf(f + bo_r, 0.f);
            float xo = xf32[par][nn];        // exact f32 state in, f32 out
            xn = (xo + 0.1f * ff * Av_r) / (1.1f + 0.1f * ff);
            xf32[par ^ 1][nn] = xn;
            out[outBase + (size_t)t * 512 + nn] = xn;
        }
        {   // pack x pairs (fp16 copy feeds next A): tid=4m / 4m+2
            float xno = __shfl_xor(xn, 2);
            if ((tid & 3) == 0)
                wrp[nn >> 1] = pkh(xn, xno);
        }
        if (tid < 64) wrp[384 + tid] = pkh(iv2.x, iv2.y);   // stage I(t+1)
        bar_lds();                           // (2) state ready for next A
    }
}

extern "C" void kernel_launch(void* const* d_in, const int* in_sizes, int n_in,
                              void* d_out, int out_size, void* d_ws, size_t ws_size,
                              hipStream_t stream)
{
    const float* I     = (const float*)d_in[0];
    const float* W_ih  = (const float*)d_in[1];
    const float* W_hh  = (const float*)d_in[2];
    const float* b_ih  = (const float*)d_in[3];
    const float* b_hh  = (const float*)d_in[4];
    const float* W_out = (const float*)d_in[5];
    const float* b_out = (const float*)d_in[6];
    const float* A     = (const float*)d_in[7];

    uint32* WREGH = (uint32*)d_ws;

    prep_kernel<<<(WREG_N + 1023) / 1024, 1024, 0, stream>>>(W_ih, W_hh, W_out, WREGH);
    scan_kernel<<<64, 1024, 0, stream>>>(I, b_ih, b_hh, b_out, A,
                                         WREGH, (float*)d_out);
}

// Round 10
// 4452.801 us; speedup vs baseline: 4.2996x; 4.2996x over previous
//
#include <hip/hip_runtime.h>
#include <hip/hip_fp16.h>

#define TT 2048
typedef unsigned int uint32;
typedef unsigned long long uint64;
typedef unsigned short ushort;

typedef _Float16 half2v __attribute__((ext_vector_type(2)));

#if defined(__has_builtin)
#  if __has_builtin(__builtin_amdgcn_fdot2)
#    define HAVE_DOT2 1
#  endif
#endif
#ifndef HAVE_DOT2
#  define HAVE_DOT2 0
#endif

// ---- d_ws layout ----
// WREGH: uint32[2][176][512]   packed fp16 weight pairs   (720896 B)
// exS  : uint64[2][64][2][256] {tag,f32} exchange         (524288 B)
#define WREG_N (2 * 176 * 512)       // 180224 dwords
#define EXA_N  (2 * 64 * 2 * 256)    // 65536 qwords

__device__ __forceinline__ float dot2(uint32 a, uint32 w, float c)
{
#if HAVE_DOT2
    return __builtin_amdgcn_fdot2(__builtin_bit_cast(half2v, a),
                                  __builtin_bit_cast(half2v, w), c, false);
#else
    half2v av = __builtin_bit_cast(half2v, a);
    half2v wv = __builtin_bit_cast(half2v, w);
    c = fmaf((float)av.x, (float)wv.x, c);
    return fmaf((float)av.y, (float)wv.y, c);
#endif
}

__device__ __forceinline__ uint32 pkh(float a, float b)
{
    __half ha = __float2half(a), hb = __float2half(b);
    ushort ua = *reinterpret_cast<ushort*>(&ha);
    ushort ub = *reinterpret_cast<ushort*>(&hb);
    return (uint32)ua | ((uint32)ub << 16);
}

// Member g's cat slice, k_slice in [0,448):
//  [0,256)   -> x cols 256g + k
//  [256,384) -> s cols 128g + (k-256)   (W_hh)
//  [384,448) -> I cols 64g  + (k-384)
__device__ __forceinline__ float getSlice(const float* __restrict__ W_ih,
                                          const float* __restrict__ W_hh,
                                          int g, int j, int k)
{
    if (k < 256) return W_ih[j * 640 + 256 * g + k];
    if (k < 384) return W_hh[j * 256 + 128 * g + (k - 256)];
    return W_ih[j * 640 + 512 + 64 * g + (k - 384)];
}

// Per-thread weight layout (member g, tid in [0,512)):
//  A slots i in [0,112): j = tid>>1, h = tid&1, slice-k pair = 112h + i, k0 = 2*pair.
//  B slots i in [112,176): s = i-112, ii = s>>2, m = s&3, nloc = tid>>1, hh = tid&1,
//    n = 256g + nloc, k0 = 128*hh + 8*ii + 2*m   (W_out row n).
__global__ void prep_kernel(const float* __restrict__ W_ih,
                            const float* __restrict__ W_hh,
                            const float* __restrict__ W_out,
                            uint32* __restrict__ WREGH,
                            uint64* __restrict__ exS)
{
    int idx = blockIdx.x * blockDim.x + threadIdx.x;
    if (idx < WREG_N) {
        int tid  = idx & 511;
        int q    = idx >> 9;       // g*176 + slot
        int g    = q / 176;
        int slot = q % 176;
        float lo, hi;
        if (slot < 112) {
            int j = tid >> 1, h = tid & 1;
            int k0 = 2 * (112 * h + slot);
            lo = getSlice(W_ih, W_hh, g, j, k0);
            hi = getSlice(W_ih, W_hh, g, j, k0 + 1);
        } else {
            int s  = slot - 112;
            int ii = s >> 2, m = s & 3;
            int nloc = tid >> 1, hh = tid & 1;
            int n  = 256 * g + nloc;
            int k0 = 128 * hh + 8 * ii + 2 * m;
            lo = W_out[n * 256 + k0];
            hi = W_out[n * 256 + k0 + 1];
        }
        WREGH[idx] = pkh(lo, hi);
    } else if (idx < WREG_N + EXA_N) {
        exS[idx - WREG_N] = 0ULL;   // tags must start 0 (ws is 0xAA-poisoned)
    }
}

// LDS-only barrier: does NOT drain vmcnt (global ops stay in flight).
__device__ __forceinline__ void bar_lds()
{
    asm volatile("s_waitcnt lgkmcnt(0)" ::: "memory");
    __builtin_amdgcn_s_barrier();
    asm volatile("" ::: "memory");
}

__global__ __launch_bounds__(512, 2)
void scan_kernel(const float* __restrict__ I,
                 const float* __restrict__ b_ih, const float* __restrict__ b_hh,
                 const float* __restrict__ b_out, const float* __restrict__ A,
                 const uint32* __restrict__ WREGH,
                 uint64* exS,
                 float* __restrict__ out)
{
    // member-slice act, packed fp16 pairs, parity double-buffered:
    //   pairs [0,128)=x-half  [128,192)=s-half  [192,224)=I-half
    __shared__ uint4 apk4[2][56];
    __shared__ uint4 s4pk[32];        // FULL s (256 vals) packed pairs
    __shared__ float xf32[256];       // exact f32 x state (own n-half)

    const int tid = threadIdx.x;
    const int bid = blockIdx.x;
    const int b   = bid & 63;     // batch element
    const int g   = bid >> 6;     // gang member (0/1)

    // ---- weights -> VGPR (static-indexed, fully unrolled, pinned) ----
    uint32 wA[112], wB[64];
    const uint32* wsrc = WREGH + (size_t)g * (176 * 512) + tid;
    #pragma unroll
    for (int i = 0; i < 112; ++i) { wA[i] = wsrc[(size_t)i * 512]; asm("" : "+v"(wA[i])); }
    #pragma unroll
    for (int i = 0; i < 64;  ++i) { wB[i] = wsrc[(size_t)(112 + i) * 512]; asm("" : "+v"(wB[i])); }

    const int h    = tid & 1;     // A k-half within lane pair (224 k each)
    const int jA   = tid >> 1;    // A output row [0,256)
    const int hh   = tid & 1;     // B k-half (128 k each)
    const int nloc = tid >> 1;    // B output row within member half

    const float bs   = ((tid & 1) == 0) ? (b_ih[jA] + b_hh[jA]) : 0.f;
    const float bo_r = ((tid & 1) == 0) ? b_out[256 * g + nloc] : 0.f;
    const float Av_r = ((tid & 1) == 0) ? A[256 * g + nloc] : 0.f;

    const size_t iBase   = (size_t)b * TT * 128 + 64 * g;
    const size_t outBase = (size_t)b * TT * 512 + 256 * g;

    {   // init buffer 0: x=0 (pairs 0..127), s=0 (128..191), I(0) (192..223)
        uint32* a0p = (uint32*)&apk4[0][0];
        if (tid < 192) a0p[tid] = 0u;
        else if (tid < 224) {
            int m = tid - 192;
            a0p[tid] = pkh(I[iBase + 2 * m], I[iBase + 2 * m + 1]);
        }
        if (tid < 256) xf32[tid] = 0.f;
    }
    __syncthreads();

    for (int t = 0; t < TT; ++t) {
        const int par = t & 1;
        const uint4* rdp = apk4[par];
        uint32*      wrp = (uint32*)apk4[par ^ 1];

        // I(t+1): issue loads early (hides HBM under compute + sync)
        float2 iv2 = make_float2(0.f, 0.f);
        if (tid < 32) {
            int tl = (t + 1 < TT) ? (t + 1) : t;
            iv2 = *(const float2*)(I + iBase + (size_t)tl * 128 + 2 * tid);
        }

        // ---- phase A: pre[jA] partial over this member's 448-k slice ----
        float a0 = 0.f, a1 = 0.f;
        #pragma unroll
        for (int i = 0; i < 28; ++i) {
            uint4 av = rdp[28 * h + i];      // 2 addrs/wave -> LDS broadcast
            a0 = dot2(av.x, wA[4 * i + 0], a0);
            a1 = dot2(av.y, wA[4 * i + 1], a1);
            a0 = dot2(av.z, wA[4 * i + 2], a0);
            a1 = dot2(av.w, wA[4 * i + 3], a1);
        }
        float acc = a0 + a1;
        acc += __shfl_xor(acc, 1);           // h0 + h1 -> full slice partial

        const uint32 tgt = (uint32)(t + 1);
        uint64* ex = exS + (size_t)(par * 64 + b) * (2 * 256);

        float sn = 0.f;
        if ((tid & 1) == 0) {
            // single 8B tagged store: payload + tag travel together
            uint64 u = ((uint64)tgt << 32) | (uint64)__float_as_uint(acc);
            __hip_atomic_store(ex + g * 256 + jA, u,
                               __ATOMIC_RELAXED, __HIP_MEMORY_SCOPE_AGENT);

            // poll the ONE peer word (it IS the payload); coalesced per wave
            const uint64* pp = ex + (1 - g) * 256 + jA;
            uint64 up;
            do {
                up = __hip_atomic_load(pp, __ATOMIC_RELAXED, __HIP_MEMORY_SCOPE_AGENT);
            } while ((uint32)(up >> 32) != tgt);

            float pre = acc + bs + __uint_as_float((uint32)up);  // fixed order
            // tanh(x) = 1 - 2/(exp(2x)+1): exact identity, branch-free
            float e = __expf(2.f * pre);
            sn = 1.f - 2.f / (e + 1.f);
        }
        {   // pack s pairs: threads 4m (jA=2m) and 4m+2 (jA=2m+1)
            float sno = __shfl_xor(sn, 2);
            if ((tid & 3) == 0) {
                int p = tid >> 2;                    // full-s pair index [0,128)
                uint32 sp = pkh(sn, sno);
                ((uint32*)s4pk)[p] = sp;             // for phase B
                int d = p - 64 * g;                  // own s-half for next A
                if (d >= 0 && d < 64) wrp[128 + d] = sp;
            }
        }
        bar_lds();                           // (1) s ready

        // ---- phase B: f[n], lane pair covers k=256 ----
        float c0 = 0.f, c1 = 0.f;
        #pragma unroll
        for (int i = 0; i < 16; ++i) {
            uint4 sv = s4pk[16 * hh + i];    // 2 addrs/wave -> LDS broadcast
            c0 = dot2(sv.x, wB[4 * i + 0], c0);
            c1 = dot2(sv.y, wB[4 * i + 1], c1);
            c0 = dot2(sv.z, wB[4 * i + 2], c0);
            c1 = dot2(sv.w, wB[4 * i + 3], c1);
        }
        float f = c0 + c1;
        f += __shfl_xor(f, 1);               // full k-sum at both pair lanes

        float xn = 0.f;
        if ((tid & 1) == 0) {
            float ff = fmaxf(f + bo_r, 0.f);
            float xo = xf32[nloc];           // exact f32 state in, f32 out
            xn = (xo + 0.1f * ff * Av_r) / (1.1f + 0.1f * ff);
            xf32[nloc] = xn;                 // same-thread RMW: no race
            out[outBase + (size_t)t * 512 + nloc] = xn;
        }
        {   // pack x pairs (fp16 copy feeds next A): threads 4m / 4m+2
            float xno = __shfl_xor(xn, 2);
            if ((tid & 3) == 0)
                wrp[tid >> 2] = pkh(xn, xno);
        }
        if (tid < 32) wrp[192 + tid] = pkh(iv2.x, iv2.y);   // stage I(t+1)
        bar_lds();                           // (2) state ready for next A
    }
}

extern "C" void kernel_launch(void* const* d_in, const int* in_sizes, int n_in,
                              void* d_out, int out_size, void* d_ws, size_t ws_size,
                              hipStream_t stream)
{
    const float* I     = (const float*)d_in[0];
    const float* W_ih  = (const float*)d_in[1];
    const float* W_hh  = (const float*)d_in[2];
    const float* b_ih  = (const float*)d_in[3];
    const float* b_hh  = (const float*)d_in[4];
    const float* W_out = (const float*)d_in[5];
    const float* b_out = (const float*)d_in[6];
    const float* A     = (const float*)d_in[7];

    uint32* WREGH = (uint32*)d_ws;
    uint64* exS   = (uint64*)((uint32*)d_ws + WREG_N);

    const int total = WREG_N + EXA_N;
    prep_kernel<<<(total + 1023) / 1024, 1024, 0, stream>>>(W_ih, W_hh, W_out,
                                                            WREGH, exS);
    scan_kernel<<<128, 512, 0, stream>>>(I, b_ih, b_hh, b_out, A,
                                         WREGH, exS, (float*)d_out);
}